// Round 2
// baseline (545.331 us; speedup 1.0000x reference)
//
#include <hip/hip_runtime.h>

// FinePreprocess: bilinear 8x8 crops of 32-channel feature maps at 2048
// sub-pixel track points per view, 16 views.
//
// features      : (1, 16, 32, 512, 512) f32   -> d_in[0]
// sample_points : (1, 16, 2048, 2)      f32   -> d_in[1]  (x, y), interior
// img_idxs      : (1, 16, 2048)         int   -> d_in[2]  (0..15, batch idx)
// out           : (1, 16, 2048, 64, 32) f32   -> d_out
//
// One wave per track, 4 tracks per 256-thread block (8 blocks/CU -> 32
// waves/CU, vs 16 with 64-thread blocks: the wg/CU slot limit was the R1
// occupancy cap). Lane = crop pixel p = cy*8 + cx. No LDS: each lane's 32
// channel outputs are exactly one aligned 128-B line (t*8KB + lane*128B),
// so per-lane float4 stores are full-line writes after L2 combining.

#define CROP    8
#define C_CH    32
#define H_DIM   512
#define W_DIM   512
#define HW_SZ   (H_DIM * W_DIM)
#define TPB     4   // tracks (waves) per block

__global__ __launch_bounds__(256, 8) void fine_preprocess_kernel(
    const float* __restrict__ feat,   // (16, 32, 512, 512) flattened
    const float* __restrict__ pts,    // (32768, 2)
    const int*   __restrict__ bids,   // (32768,)
    float*       __restrict__ out,    // (32768, 64, 32)
    int n_tracks)
{
    const int wid  = threadIdx.x >> 6;     // wave id in block = track slot
    const int lane = threadIdx.x & 63;     // pixel p = cy*8 + cx
    const int t    = blockIdx.x * TPB + wid;
    if (t >= n_tracks) return;

    const int cy = lane >> 3;
    const int cx = lane & 7;

    // Wave-uniform loads (scalarized by compiler)
    const float px = pts[2 * t];
    const float py = pts[2 * t + 1];
    const int   b  = bids[t];

    // lin = linspace(-4, 4, 8): -4 + k*(8/7)
    const float step = 8.0f / 7.0f;
    const float X = px + fmaf(step, (float)cx, -4.0f);
    const float Y = py + fmaf(step, (float)cy, -4.0f);

    const float x0f = floorf(X);
    const float y0f = floorf(Y);
    const float wx  = X - x0f;
    const float wy  = Y - y0f;
    const int   x0  = (int)x0f;
    const int   y0  = (int)y0f;
    const int   x1  = x0 + 1;
    const int   y1  = y0 + 1;

    // Validity masks (always 1 for interior points; kept for exact reference
    // semantics) folded into the 4 bilinear weights.
    const float my0 = (y0 >= 0 && y0 < H_DIM) ? 1.0f : 0.0f;
    const float my1 = (y1 >= 0 && y1 < H_DIM) ? 1.0f : 0.0f;
    const float mx0 = (x0 >= 0 && x0 < W_DIM) ? 1.0f : 0.0f;
    const float mx1 = (x1 >= 0 && x1 < W_DIM) ? 1.0f : 0.0f;

    const int x0c = min(max(x0, 0), W_DIM - 1);
    const int x1c = min(max(x1, 0), W_DIM - 1);
    const int y0c = min(max(y0, 0), H_DIM - 1);
    const int y1c = min(max(y1, 0), H_DIM - 1);

    const float w00 = (1.0f - wy) * (1.0f - wx) * (my0 * mx0);
    const float w01 = (1.0f - wy) * wx          * (my0 * mx1);
    const float w10 = wy          * (1.0f - wx) * (my1 * mx0);
    const float w11 = wy          * wx          * (my1 * mx1);

    // Element offsets into channel-0 plane of view b
    const int plane0 = b * (C_CH * HW_SZ);
    const int r0     = plane0 + y0c * W_DIM;
    const int r1     = plane0 + y1c * W_DIM;
    const int o00 = r0 + x0c;
    const int o01 = r0 + x1c;
    const int o10 = r1 + x0c;
    const int o11 = r1 + x1c;

    // Each lane owns one 128-B output line: out[t][p][0..31]
    float* __restrict__ obase = out + (size_t)t * (CROP * CROP * C_CH)
                                    + lane * C_CH;

    #pragma unroll 1
    for (int c0 = 0; c0 < C_CH; c0 += 8) {
        float a[8];
        #pragma unroll
        for (int cc = 0; cc < 8; ++cc) {
            const int off = (c0 + cc) * HW_SZ;
            const float v00 = feat[o00 + off];
            const float v01 = feat[o01 + off];
            const float v10 = feat[o10 + off];
            const float v11 = feat[o11 + off];
            a[cc] = fmaf(v00, w00, fmaf(v01, w01, fmaf(v10, w10, v11 * w11)));
        }
        float4* o4 = reinterpret_cast<float4*>(obase + c0);
        o4[0] = make_float4(a[0], a[1], a[2], a[3]);
        o4[1] = make_float4(a[4], a[5], a[6], a[7]);
    }
}

extern "C" void kernel_launch(void* const* d_in, const int* in_sizes, int n_in,
                              void* d_out, int out_size, void* d_ws, size_t ws_size,
                              hipStream_t stream) {
    const float* feat = (const float*)d_in[0];
    const float* pts  = (const float*)d_in[1];
    const int*   bids = (const int*)d_in[2];
    float*       out  = (float*)d_out;

    const int n_tracks = in_sizes[2];   // 16 * 2048 = 32768
    const int blocks   = (n_tracks + TPB - 1) / TPB;

    fine_preprocess_kernel<<<blocks, TPB * 64, 0, stream>>>(feat, pts, bids,
                                                            out, n_tracks);
}

// Round 3
// 457.738 us; speedup vs baseline: 1.1914x; 1.1914x over previous
//
#include <hip/hip_runtime.h>

// FinePreprocess: bilinear 8x8 crops of 32-channel feature maps at 2048
// sub-pixel track points per view, 16 views.
//
// features      : (1, 16, 32, 512, 512) f32   -> d_in[0]
// sample_points : (1, 16, 2048, 2)      f32   -> d_in[1]  (x, y), interior
// img_idxs      : (1, 16, 2048)         int   -> d_in[2]  (0..15)
// out           : (1, 16, 2048, 64, 32) f32   -> d_out
//
// One wave per track, 4 tracks per 256-thread block.
// Lane mapping chosen for STORE coalescing without LDS (R2 lesson: per-lane
// 128B-strided float4 stores caused 1.7x WRITE_SIZE and lost to R1's LDS
// transpose):
//   lane = (cx = lane>>3, channel quad c0 = (lane&7)*4), loop over cy.
//   out offset = cy*256 + lane*4  -> one contiguous 1KiB store per wave
//   per iteration; WRITE_SIZE == output bytes exactly.
// X weights are lane-fixed (computed once); Y weights wave-uniform per cy
// (scalarized). 16 gather loads + 16 FMA per lane per iteration.

#define CROP    8
#define C_CH    32
#define H_DIM   512
#define W_DIM   512
#define HW_SZ   (H_DIM * W_DIM)
#define TPB     4   // tracks (waves) per block

__global__ __launch_bounds__(256, 8) void fine_preprocess_kernel(
    const float* __restrict__ feat,   // (16, 32, 512, 512) flattened
    const float* __restrict__ pts,    // (32768, 2)
    const int*   __restrict__ bids,   // (32768,)
    float*       __restrict__ out,    // (32768, 64, 32)
    int n_tracks)
{
    const int wid  = threadIdx.x >> 6;     // wave id in block = track slot
    const int lane = threadIdx.x & 63;
    const int t    = blockIdx.x * TPB + wid;
    if (t >= n_tracks) return;

    const int cx = lane >> 3;          // crop column 0..7
    const int c0 = (lane & 7) * 4;     // channel quad base 0,4,...,28

    // Wave-uniform loads (scalarized)
    const float px = pts[2 * t];
    const float py = pts[2 * t + 1];
    const int   b  = bids[t];

    // lin = linspace(-4, 4, 8): -4 + k*(8/7)
    const float step = 8.0f / 7.0f;

    // --- X part: fixed per lane, computed once ---
    const float X   = px + fmaf(step, (float)cx, -4.0f);
    const float x0f = floorf(X);
    const float wx  = X - x0f;
    const int   x0  = (int)x0f;
    const int   x1  = x0 + 1;
    const float mx0 = (x0 >= 0 && x0 < W_DIM) ? 1.0f : 0.0f;
    const float mx1 = (x1 >= 0 && x1 < W_DIM) ? 1.0f : 0.0f;
    const int   x0c = min(max(x0, 0), W_DIM - 1);
    const int   x1c = min(max(x1, 0), W_DIM - 1);

    // Base of this lane's first channel plane within view b
    const int plane0 = b * (C_CH * HW_SZ) + c0 * HW_SZ;

    float* __restrict__ obase = out + (size_t)t * (CROP * CROP * C_CH)
                                    + lane * 4;

    #pragma unroll 1
    for (int cy = 0; cy < CROP; ++cy) {
        // --- Y part: wave-uniform per iteration (scalar) ---
        const float Y   = py + fmaf(step, (float)cy, -4.0f);
        const float y0f = floorf(Y);
        const float wy  = Y - y0f;
        const int   y0  = (int)y0f;
        const int   y1  = y0 + 1;
        const float my0 = (y0 >= 0 && y0 < H_DIM) ? 1.0f : 0.0f;
        const float my1 = (y1 >= 0 && y1 < H_DIM) ? 1.0f : 0.0f;
        const int   y0c = min(max(y0, 0), H_DIM - 1);
        const int   y1c = min(max(y1, 0), H_DIM - 1);

        const float w00 = (1.0f - wy) * (1.0f - wx) * (my0 * mx0);
        const float w01 = (1.0f - wy) * wx          * (my0 * mx1);
        const float w10 = wy          * (1.0f - wx) * (my1 * mx0);
        const float w11 = wy          * wx          * (my1 * mx1);

        const int r0  = y0c * W_DIM;
        const int r1  = y1c * W_DIM;
        const int o00 = plane0 + r0 + x0c;
        const int o01 = plane0 + r0 + x1c;
        const int o10 = plane0 + r1 + x0c;
        const int o11 = plane0 + r1 + x1c;

        float a[4];
        #pragma unroll
        for (int cc = 0; cc < 4; ++cc) {
            const int off = cc * HW_SZ;
            const float v00 = feat[o00 + off];
            const float v01 = feat[o01 + off];
            const float v10 = feat[o10 + off];
            const float v11 = feat[o11 + off];
            a[cc] = fmaf(v00, w00, fmaf(v01, w01, fmaf(v10, w10, v11 * w11)));
        }

        // Wave-contiguous 1 KiB store: lanes 0..63 cover [cy*256, cy*256+256)
        *reinterpret_cast<float4*>(obase + cy * 256) =
            make_float4(a[0], a[1], a[2], a[3]);
    }
}

extern "C" void kernel_launch(void* const* d_in, const int* in_sizes, int n_in,
                              void* d_out, int out_size, void* d_ws, size_t ws_size,
                              hipStream_t stream) {
    const float* feat = (const float*)d_in[0];
    const float* pts  = (const float*)d_in[1];
    const int*   bids = (const int*)d_in[2];
    float*       out  = (float*)d_out;

    const int n_tracks = in_sizes[2];   // 16 * 2048 = 32768
    const int blocks   = (n_tracks + TPB - 1) / TPB;

    fine_preprocess_kernel<<<blocks, TPB * 64, 0, stream>>>(feat, pts, bids,
                                                            out, n_tracks);
}

// Round 5
// 285.028 us; speedup vs baseline: 1.9133x; 1.6059x over previous
//
#include <hip/hip_runtime.h>

// FinePreprocess: bilinear 8x8 crops of 32-channel feature maps at 2048
// sub-pixel track points per view, 16 views.
//
// features      : (1, 16, 32, 512, 512) f32   -> d_in[0]
// sample_points : (1, 16, 2048, 2)      f32   -> d_in[1]  (x, y), interior
// img_idxs      : (1, 16, 2048)         int   -> d_in[2]  (0..15)
// out           : (1, 16, 2048, 64, 32) f32   -> d_out
//
// One wave per track, 4 tracks per 256-thread block (32 waves/CU).
// lane = (cx = lane>>3, channel quad c0 = (lane&7)*4); loop over crop row r.
// Store: out elem = r*256 + lane*4 -> one contiguous 1 KiB nt-store per pass
// (R2 lesson: strided per-lane stores blow up WRITE_SIZE; R3 confirmed this
// mapping gives WRITE_SIZE == output exactly).
//
// R3 lesson: cross-pass row reuse (y1 row of pass r == y0 row of pass r+1)
// died in L1 at 1 KB/wave effective capacity -> refetched from L2 every
// pass. Fix: REGISTER row cache. Row step 8/7 in (1,2) => floor advance is
// 1 or 2; on advance-1 (6/7 of passes) shift the y1-row registers into the
// y0 slots and load only the 8 new y1-row values. Wave-uniform branch.
//
// Points are interior (uniform*(512-16)+8, +/-4 crop): taps in [3,509] --
// masks are provably 1 and clamps no-ops, so they are dropped entirely.
//
// R4 lesson: __builtin_nontemporal_store needs a NATIVE vector type, not
// HIP_vector_type<float,4> -> use ext_vector_type(4).

#define CROP    8
#define C_CH    32
#define H_DIM   512
#define W_DIM   512
#define HW_SZ   (H_DIM * W_DIM)
#define TPB     4   // tracks (waves) per block
#define STEP    (8.0f / 7.0f)

typedef float f32x4 __attribute__((ext_vector_type(4)));

__global__ __launch_bounds__(256, 8) void fine_preprocess_kernel(
    const float* __restrict__ feat,   // (16, 32, 512, 512) flattened
    const float* __restrict__ pts,    // (32768, 2)
    const int*   __restrict__ bids,   // (32768,)
    float*       __restrict__ out,    // (32768, 64, 32)
    int n_tracks)
{
    const int wid  = threadIdx.x >> 6;
    const int lane = threadIdx.x & 63;
    const int t    = blockIdx.x * TPB + wid;
    if (t >= n_tracks) return;

    const int cx = lane >> 3;          // crop column 0..7
    const int c0 = (lane & 7) << 2;    // channel quad base 0,4,...,28

    // Wave-uniform (scalarized)
    const float px = pts[2 * t];
    const float py = pts[2 * t + 1];
    const int   b  = bids[t];

    // X part: fixed per lane
    const float X   = px + fmaf(STEP, (float)cx, -4.0f);
    const float x0f = floorf(X);
    const float wx  = X - x0f;
    const int   x0  = (int)x0f;

    // Per-lane base: view b, channel c0, row 0, column x0
    const float* __restrict__ fp =
        feat + ((size_t)b * C_CH + c0) * HW_SZ + x0;

    float* __restrict__ obase = out + (size_t)t * (CROP * CROP * C_CH)
                                    + lane * 4;

    // Register row cache: y0-row and y1-row taps at x0 / x0+1, 4 channels.
    float a00[4], a01[4], a10[4], a11[4];
    int iy1 = -12345;   // previous pass's y1 (invalid -> full load first pass)

    #pragma unroll 1
    for (int r = 0; r < CROP; ++r) {
        const float Y   = py + fmaf(STEP, (float)r, -4.0f);
        const float y0f = floorf(Y);
        const float wy  = Y - y0f;
        const int   iy0 = (int)y0f;

        if (iy0 == iy1) {
            // advance-1: previous y1 row becomes this pass's y0 row
            #pragma unroll
            for (int cc = 0; cc < 4; ++cc) {
                a00[cc] = a10[cc];
                a01[cc] = a11[cc];
            }
            const int ro = (iy0 + 1) * W_DIM;
            #pragma unroll
            for (int cc = 0; cc < 4; ++cc) {
                a10[cc] = fp[cc * HW_SZ + ro];
                a11[cc] = fp[cc * HW_SZ + ro + 1];
            }
        } else {
            // advance-2 (or first pass): load both rows
            const int r0o = iy0 * W_DIM;
            const int r1o = r0o + W_DIM;
            #pragma unroll
            for (int cc = 0; cc < 4; ++cc) {
                a00[cc] = fp[cc * HW_SZ + r0o];
                a01[cc] = fp[cc * HW_SZ + r0o + 1];
                a10[cc] = fp[cc * HW_SZ + r1o];
                a11[cc] = fp[cc * HW_SZ + r1o + 1];
            }
        }
        iy1 = iy0 + 1;

        const float w00 = (1.0f - wy) * (1.0f - wx);
        const float w01 = (1.0f - wy) * wx;
        const float w10 = wy * (1.0f - wx);
        const float w11 = wy * wx;

        f32x4 o;
        o.x = fmaf(a00[0], w00, fmaf(a01[0], w01, fmaf(a10[0], w10, a11[0] * w11)));
        o.y = fmaf(a00[1], w00, fmaf(a01[1], w01, fmaf(a10[1], w10, a11[1] * w11)));
        o.z = fmaf(a00[2], w00, fmaf(a01[2], w01, fmaf(a10[2], w10, a11[2] * w11)));
        o.w = fmaf(a00[3], w00, fmaf(a01[3], w01, fmaf(a10[3], w10, a11[3] * w11)));

        // Contiguous 1 KiB wave store; nontemporal: output is never re-read,
        // keep L2 capacity for the gather stream.
        __builtin_nontemporal_store(o,
            reinterpret_cast<f32x4*>(obase + r * 256));
    }
}

extern "C" void kernel_launch(void* const* d_in, const int* in_sizes, int n_in,
                              void* d_out, int out_size, void* d_ws, size_t ws_size,
                              hipStream_t stream) {
    const float* feat = (const float*)d_in[0];
    const float* pts  = (const float*)d_in[1];
    const int*   bids = (const int*)d_in[2];
    float*       out  = (float*)d_out;

    const int n_tracks = in_sizes[2];   // 16 * 2048 = 32768
    const int blocks   = (n_tracks + TPB - 1) / TPB;

    fine_preprocess_kernel<<<blocks, TPB * 64, 0, stream>>>(feat, pts, bids,
                                                            out, n_tracks);
}

// Round 6
// 282.034 us; speedup vs baseline: 1.9336x; 1.0106x over previous
//
#include <hip/hip_runtime.h>

// FinePreprocess: bilinear 8x8 crops of 32-channel feature maps at 2048
// sub-pixel track points per view, 16 views.
//
// features      : (1, 16, 32, 512, 512) f32   -> d_in[0]
// sample_points : (1, 16, 2048, 2)      f32   -> d_in[1]  (x, y), interior
// img_idxs      : (1, 16, 2048)         int   -> d_in[2]  (0..15)
// out           : (1, 16, 2048, 64, 32) f32   -> d_out
//
// One wave per track, 4 tracks per 256-thread block.
// lane = (cx = lane>>3, channel quad c0 = (lane&7)*4).
// Store: out elem = r*256 + lane*4 -> contiguous 1 KiB nt-store per row
// (R2/R3 lesson: this is the only mapping with WRITE_SIZE == output).
//
// R5 lesson: per-row load->wait->fma loop leaves only ~8 loads in flight
// per wave; kernel is latency-bound at 42% HBM BW. Fix: BATCH the gathers.
// All row taps live in rows B0..B0+9 (B0 = floor(py-4); row step 8/7).
// Two-phase register window (48 VGPR of tap data in flight):
//   phase 1: load rows B0..B0+5   (48 loads, issued back-to-back)
//            compute output rows 0..3
//   phase 2: shift rows 4,5 -> 0,1; load rows B0+6..B0+9 (32 loads)
//            compute output rows 4..7
// Row selection per output row r is a wave-uniform 2-way branch between
// compile-time register indices {K,K+1} vs {K+1,K+2}, K = floor(8r/7):
// guaranteed because lin[r]+4 is >= 1/7 from any integer for r=1..6 (float
// error 3e-5 << 1/7), and lin[0] = -4, lin[7] = +4 are forced EXACT
// (py +/- 4 is exactly representable for py in [8,504]).
//
// Points are interior: taps in [3,509] -- masks provably 1, clamps no-ops.

#define CROP    8
#define C_CH    32
#define H_DIM   512
#define W_DIM   512
#define HW_SZ   (H_DIM * W_DIM)
#define TPB     4   // tracks (waves) per block

typedef float f32x4 __attribute__((ext_vector_type(4)));

__global__ __launch_bounds__(256, 6) void fine_preprocess_kernel(
    const float* __restrict__ feat,   // (16, 32, 512, 512) flattened
    const float* __restrict__ pts,    // (32768, 2)
    const int*   __restrict__ bids,   // (32768,)
    float*       __restrict__ out,    // (32768, 64, 32)
    int n_tracks)
{
    const int wid  = threadIdx.x >> 6;
    const int lane = threadIdx.x & 63;
    const int t    = blockIdx.x * TPB + wid;
    if (t >= n_tracks) return;

    const int cx = lane >> 3;          // crop column 0..7
    const int c0 = (lane & 7) << 2;    // channel quad base

    // Wave-uniform (scalarized)
    const float px = pts[2 * t];
    const float py = pts[2 * t + 1];
    const int   b  = bids[t];

    // X part: fixed per lane (lin endpoint forced exact)
    const float linx = (cx == 7) ? 4.0f : fmaf((float)cx, 8.0f / 7.0f, -4.0f);
    const float X   = px + linx;
    const float x0f = floorf(X);
    const float wx  = X - x0f;
    const int   x0  = (int)x0f;

    const int B0 = (int)floorf(py - 4.0f);   // wave-uniform top row

    // Per-lane base: view b, channel c0, row B0, column x0
    const float* __restrict__ fp =
        feat + ((size_t)b * C_CH + c0) * HW_SZ + (size_t)B0 * W_DIM + x0;

    float* __restrict__ obase =
        out + (size_t)t * (CROP * CROP * C_CH) + lane * 4;

    // Tap register window: 6 rows x {x0, x0+1} x 4 channels
    float va[6][4], vb[6][4];

    // ---- phase 1 loads: rows B0 .. B0+5, 48 independent loads ----
    #pragma unroll
    for (int j = 0; j < 6; ++j) {
        #pragma unroll
        for (int cc = 0; cc < 4; ++cc) {
            va[j][cc] = fp[j * W_DIM + cc * HW_SZ];
            vb[j][cc] = fp[j * W_DIM + cc * HW_SZ + 1];
        }
    }

#define EMIT(r, ja, jb, wy_) do {                                             \
    const float wy__ = (wy_);                                                 \
    const float w00 = (1.0f - wy__) * (1.0f - wx);                            \
    const float w01 = (1.0f - wy__) * wx;                                     \
    const float w10 = wy__ * (1.0f - wx);                                     \
    const float w11 = wy__ * wx;                                              \
    f32x4 o;                                                                  \
    o.x = fmaf(va[ja][0], w00, fmaf(vb[ja][0], w01,                           \
          fmaf(va[jb][0], w10, vb[jb][0] * w11)));                            \
    o.y = fmaf(va[ja][1], w00, fmaf(vb[ja][1], w01,                           \
          fmaf(va[jb][1], w10, vb[jb][1] * w11)));                            \
    o.z = fmaf(va[ja][2], w00, fmaf(vb[ja][2], w01,                           \
          fmaf(va[jb][2], w10, vb[jb][2] * w11)));                            \
    o.w = fmaf(va[ja][3], w00, fmaf(vb[ja][3], w01,                           \
          fmaf(va[jb][3], w10, vb[jb][3] * w11)));                            \
    __builtin_nontemporal_store(o,                                            \
        reinterpret_cast<f32x4*>(obase + (r) * 256));                         \
} while (0)

    // r = 0: Y = py - 4 (exact), y0 == B0 exactly
    {
        const float wy = (py - 4.0f) - (float)B0;
        EMIT(0, 0, 1, wy);
    }

#define ROW_P1(r, K) do {                                                     \
    const float Y   = py + fmaf((float)(r), 8.0f / 7.0f, -4.0f);              \
    const float y0f = floorf(Y);                                              \
    const float wy  = Y - y0f;                                                \
    if ((int)y0f - B0 == (K)) EMIT(r, (K), (K) + 1, wy);                      \
    else                      EMIT(r, (K) + 1, (K) + 2, wy);                  \
} while (0)

    ROW_P1(1, 1);
    ROW_P1(2, 2);
    ROW_P1(3, 3);

    // ---- phase 2: rows B0+4 .. B0+9 (indices shifted by -4) ----
    #pragma unroll
    for (int cc = 0; cc < 4; ++cc) {
        va[0][cc] = va[4][cc]; vb[0][cc] = vb[4][cc];
        va[1][cc] = va[5][cc]; vb[1][cc] = vb[5][cc];
    }
    #pragma unroll
    for (int j = 2; j < 6; ++j) {
        #pragma unroll
        for (int cc = 0; cc < 4; ++cc) {
            va[j][cc] = fp[(j + 4) * W_DIM + cc * HW_SZ];
            vb[j][cc] = fp[(j + 4) * W_DIM + cc * HW_SZ + 1];
        }
    }

#define ROW_P2(r, K) do {                                                     \
    const float Y   = py + fmaf((float)(r), 8.0f / 7.0f, -4.0f);              \
    const float y0f = floorf(Y);                                              \
    const float wy  = Y - y0f;                                                \
    if ((int)y0f - B0 == (K) + 4) EMIT(r, (K), (K) + 1, wy);                  \
    else                          EMIT(r, (K) + 1, (K) + 2, wy);              \
} while (0)

    ROW_P2(4, 0);
    ROW_P2(5, 1);
    ROW_P2(6, 2);

    // r = 7: Y = py + 4 (exact), y0 == B0 + 8 -> shifted indices 4,5
    {
        const float wy = (py + 4.0f) - (float)(B0 + 8);
        EMIT(7, 4, 5, wy);
    }
}

extern "C" void kernel_launch(void* const* d_in, const int* in_sizes, int n_in,
                              void* d_out, int out_size, void* d_ws, size_t ws_size,
                              hipStream_t stream) {
    const float* feat = (const float*)d_in[0];
    const float* pts  = (const float*)d_in[1];
    const int*   bids = (const int*)d_in[2];
    float*       out  = (float*)d_out;

    const int n_tracks = in_sizes[2];   // 16 * 2048 = 32768
    const int blocks   = (n_tracks + TPB - 1) / TPB;

    fine_preprocess_kernel<<<blocks, TPB * 64, 0, stream>>>(feat, pts, bids,
                                                            out, n_tracks);
}